// Round 6
// baseline (3758.550 us; speedup 1.0000x reference)
//
#include <hip/hip_runtime.h>
#include <cstdint>

#define E_EXP 8
#define BATCH 8192
#define D0 480
#define D1 512
#define D2 512
#define D3 363
#define KP 512      // padded per-expert K
#define N3PAD 384

typedef _Float16 f16x8 __attribute__((ext_vector_type(8)));
typedef float f32x4 __attribute__((ext_vector_type(4)));
typedef unsigned short u16;

__device__ __forceinline__ u16 f2h(float f) {
    _Float16 h = (_Float16)f;
    return __builtin_bit_cast(u16, h);
}

// async global->LDS, 16B per lane; LDS dest = wave-uniform base + lane*16
__device__ __forceinline__ void async16(const u16* g, u16* s) {
    __builtin_amdgcn_global_load_lds(
        reinterpret_cast<const __attribute__((address_space(1))) void*>(
            reinterpret_cast<uintptr_t>(g)),
        reinterpret_cast<__attribute__((address_space(3))) void*>(
            reinterpret_cast<uintptr_t>(s)),
        16, 0, 0);
}

// W[e][o][i] fp32 -> wf[e][o][0..511] fp16, zero-padded in o (to OUTP) and i (to 512)
__device__ __forceinline__ void pack_seg(const float* __restrict__ src,
                                         u16* __restrict__ dst,
                                         int OUT_src, int OUTP, int IN_src) {
    int total = E_EXP * OUTP * 128;
    int in4 = IN_src >> 2;
    for (int idx = blockIdx.x * blockDim.x + threadIdx.x; idx < total;
         idx += gridDim.x * blockDim.x) {
        int e = idx / (OUTP * 128);
        int r = idx - e * OUTP * 128;
        int o = r >> 7;
        int k4 = r & 127;
        ushort4 w;
        if (o < OUT_src && k4 < in4) {
            const float4 v = *reinterpret_cast<const float4*>(
                src + ((size_t)e * OUT_src + o) * IN_src + (k4 << 2));
            w.x = f2h(v.x); w.y = f2h(v.y); w.z = f2h(v.z); w.w = f2h(v.w);
        } else {
            w.x = 0; w.y = 0; w.z = 0; w.w = 0;
        }
        *reinterpret_cast<ushort4*>(dst + ((size_t)e * OUTP + o) * KP + (k4 << 2)) = w;
    }
}

// One prep kernel: pack W1/W2/W3 fp32->fp16(padded) AND pad x.
__global__ void pack_all(const float* __restrict__ x,
                         const float* __restrict__ W1, const float* __restrict__ W2,
                         const float* __restrict__ W3, u16* __restrict__ xp,
                         u16* __restrict__ wf1, u16* __restrict__ wf2,
                         u16* __restrict__ wf3) {
    pack_seg(W1, wf1, 512, 512, D0);
    pack_seg(W2, wf2, 512, 512, D1);
    pack_seg(W3, wf3, D3, N3PAD, D2);
    // x (8192x480 fp32) -> xp (8192x512 fp16, zero-padded)
    int total = BATCH * 128;
    for (int idx = blockIdx.x * blockDim.x + threadIdx.x; idx < total;
         idx += gridDim.x * blockDim.x) {
        int b = idx >> 7, k4 = idx & 127;
        ushort4 w;
        if (k4 < 120) {
            const float4 v = *reinterpret_cast<const float4*>(
                x + (size_t)b * D0 + (k4 << 2));
            w.x = f2h(v.x); w.y = f2h(v.y); w.z = f2h(v.z); w.w = f2h(v.w);
        } else {
            w.x = 0; w.y = 0; w.z = 0; w.w = 0;
        }
        *reinterpret_cast<ushort4*>(xp + (size_t)b * KP + (k4 << 2)) = w;
    }
}

// All-expert fused blended GEMM, DOUBLE-BUFFERED (BK=32, 16 passes):
//   acc[m][n] = sum_e bl[e,m] * (A @ W_e^T)[m,n]   (in-register blend on A)
// Tile 256x64 and LDS layout identical to the verified round-0 kernel.
// CHANGE (round 6): 16 waves of 64x16 wave-tiles (4m x 4n) instead of
// 8 waves of 64x32 -- total waves/SIMD 2 -> 4 at the SAME tile/LDS/staging.
// Rationale: measured plateau = MFMA pipe ~40% of wall (per-SIMD) + LDS pipe
// ~40% (per-CU) on DIFFERENT pipes; 2 waves/SIMD can't overlap them. Cost:
// A-frag reads x2 (LDS pipe +20%), per-wave VALU:MFMA x2 (VALU pipe ~16K cyc
// /SIMD/layer, still << MFMA 40K). Gain: 2x latency hiding.
// [session ledger: r0 = 43.0us/gemm (verified best). Falsified: 32x32x16
//  (-6%), counted-vmcnt-only (neutral), 128-row-tile blocks (-5%), 4-phase
//  interleave (-130%). This round: wave-shape, a new mechanism.]
__global__ __launch_bounds__(1024, 4) void gemm_all(
    const u16* __restrict__ A, const u16* __restrict__ Bw,
    const float* __restrict__ blend, const float* __restrict__ bias,
    u16* __restrict__ out, int OUTP, int OUTR, int nbn, int mode) {
    __shared__ __align__(16) u16 S[49152];  // 96 KB = 2 x (As 8192 + Bs 16384)
    const int tid = threadIdx.x;
    const int w = tid >> 6, lane = tid & 63;   // 16 waves
    const int wm3 = w & 3, wn3 = w >> 2;       // 4 m-waves x 4 n-waves
    const int q = lane >> 4, l15 = lane & 15;

    const int id = blockIdx.x;
    const int xcd = id & 7;
    const int j = id >> 3;
    const int bm = ((j & 3) << 3) + xcd;  // 0..31 (256-row tiles), pinned to XCD
    const int bn = j >> 2;                // 0..nbn-1

    f32x4 acc[4];  // 4 m-frags x 1 n-frag (wave tile 64x16)
#pragma unroll
    for (int mi = 0; mi < 4; ++mi) acc[mi] = (f32x4){0.f, 0.f, 0.f, 0.f};

    // per-lane blend scalars: blh[e][mi] = blend[e, bm*256 + wm3*64 + mi*16 + l15]
    _Float16 blh[8][4];
#pragma unroll
    for (int e = 0; e < 8; ++e)
#pragma unroll
        for (int mi = 0; mi < 4; ++mi)
            blh[e][mi] = (_Float16)blend[e * BATCH + bm * 256 + wm3 * 64 +
                                         mi * 16 + l15];

    // staging geometry: 1KB chunk = 16 rows x 32k; lane = r*4 + s
    const int l4r = lane >> 2;                 // row in chunk
    const int l4s = lane & 3;                  // phys slot
    const int ks8 = (l4s ^ (l4r & 3)) << 3;    // swizzled k elem offset
    const size_t EST = (size_t)OUTP * KP;      // expert stride in Bw
    // wave w stages: A rows [16w,16w+16) (1 call); B expert w>>1,
    // rows [32*(w&1), +32) (2 calls). 48 x 1KB chunks total per kt.
    const int half = w & 1;
    const u16* gA0 = A + (size_t)(bm * 256 + w * 16 + l4r) * KP + ks8;
    const u16* gB0 = Bw + (size_t)(w >> 1) * EST +
                     (size_t)(bn * 64 + half * 32 + l4r) * KP + ks8;
    const size_t R16 = (size_t)16 * KP;
    const int aBase = w * 512;                          // As dst (elems)
    const int bBase = 8192 + (w >> 1) * 2048 + half * 1024;  // Bs dst

    // fragment read offsets (loop-invariant)
    const int ra = (q ^ (l15 & 3)) << 3;       // swizzled k-slot for reads
    const int arow[4] = {(wm3 * 64 + 0 * 16 + l15) * 32 + ra,
                         (wm3 * 64 + 1 * 16 + l15) * 32 + ra,
                         (wm3 * 64 + 2 * 16 + l15) * 32 + ra,
                         (wm3 * 64 + 3 * 16 + l15) * 32 + ra};
    const int brow = (wn3 * 16 + l15) * 32 + ra;

    auto stage = [&](int kt, int p) {
        const int ko = kt << 5;
        u16* buf = S + p * 24576;
        async16(gA0 + ko, buf + aBase);
        async16(gB0 + ko, buf + bBase);
        async16(gB0 + R16 + ko, buf + bBase + 512);
    };

    stage(0, 0);
    __syncthreads();

#pragma unroll 2
    for (int kt = 0; kt < 16; ++kt) {
        const int p = kt & 1;
        if (kt < 15) stage(kt + 1, p ^ 1);
        const u16* As_ = S + p * 24576;
        const u16* Bs_ = As_ + 8192;
        f16x8 af[4];
#pragma unroll
        for (int mi = 0; mi < 4; ++mi)
            af[mi] = *reinterpret_cast<const f16x8*>(&As_[arow[mi]]);
#pragma unroll
        for (int e = 0; e < 8; ++e) {
            f16x8 bf = *reinterpret_cast<const f16x8*>(&Bs_[e * 2048 + brow]);
#pragma unroll
            for (int mi = 0; mi < 4; ++mi) {
                f16x8 as = af[mi] * blh[e][mi];
                acc[mi] = __builtin_amdgcn_mfma_f32_16x16x32_f16(
                    as, bf, acc[mi], 0, 0, 0);
            }
        }
        __syncthreads();
    }

    // fused epilogue: blended bias from LDS tiles, optional ELU, fp16 store
    float* Blf = reinterpret_cast<float*>(S);           // [256][8]
    float* Bif = reinterpret_cast<float*>(S + 16384);   // [64][8] (32 KB in)
    for (int idx = tid; idx < 2048; idx += 1024) {
        int e = idx >> 8, r = idx & 255;
        Blf[r * 8 + e] = blend[e * BATCH + bm * 256 + r];
    }
    if (tid < 512) {
        int e = tid >> 6, c = tid & 63;
        int cg = bn * 64 + c;
        Bif[c * 8 + e] = (cg < OUTR) ? bias[e * OUTR + cg] : 0.f;
    }
    __syncthreads();

    const int col_l = wn3 * 16 + l15;
    const int gcol = bn * 64 + col_l;
    float bif[8];
#pragma unroll
    for (int e = 0; e < 8; ++e) bif[e] = Bif[col_l * 8 + e];
#pragma unroll
    for (int mi = 0; mi < 4; ++mi) {
#pragma unroll
        for (int r = 0; r < 4; ++r) {
            int rl = wm3 * 64 + mi * 16 + q * 4 + r;
            float bb = 0.f;
#pragma unroll
            for (int e = 0; e < 8; ++e) bb += Blf[rl * 8 + e] * bif[e];
            float v = acc[mi][r] + bb;
            if (mode == 0) v = v > 0.f ? v : expm1f(v);
            out[(size_t)(bm * 256 + rl) * OUTP + gcol] = f2h(v);
        }
    }
}

// softmax over D3=363 of fp16 logits (bias already applied) -> fp32 out.
__global__ __launch_bounds__(128) void softmax_rows(
    const u16* __restrict__ P, float* __restrict__ out) {
    const int b = blockIdx.x;
    const int tid = threadIdx.x, lane = tid & 63, w = tid >> 6;
    float v[3];
    int n = 0;
    float mx = -3.4e38f;
    for (int i = tid; i < D3; i += 128) {
        float s = (float)*reinterpret_cast<const _Float16*>(
            P + (size_t)b * N3PAD + i);
        v[n] = s; mx = fmaxf(mx, s); ++n;
    }
#pragma unroll
    for (int off = 32; off >= 1; off >>= 1) mx = fmaxf(mx, __shfl_xor(mx, off, 64));
    __shared__ float sm[4];
    if (lane == 0) sm[w] = mx;
    __syncthreads();
    mx = fmaxf(sm[0], sm[1]);
    float s = 0.f;
    for (int jj = 0; jj < n; ++jj) { v[jj] = expf(v[jj] - mx); s += v[jj]; }
#pragma unroll
    for (int off = 32; off >= 1; off >>= 1) s += __shfl_xor(s, off, 64);
    if (lane == 0) sm[2 + w] = s;
    __syncthreads();
    float inv = 1.f / (sm[2] + sm[3]);
    n = 0;
    for (int i = tid; i < D3; i += 128) { out[(size_t)b * D3 + i] = v[n] * inv; ++n; }
}

extern "C" void kernel_launch(void* const* d_in, const int* in_sizes, int n_in,
                              void* d_out, int out_size, void* d_ws, size_t ws_size,
                              hipStream_t stream) {
    const float* x = (const float*)d_in[0];
    const float* blend = (const float*)d_in[1];
    const float* W1 = (const float*)d_in[2];
    const float* b1 = (const float*)d_in[3];
    const float* W2 = (const float*)d_in[4];
    const float* b2 = (const float*)d_in[5];
    const float* W3 = (const float*)d_in[6];
    const float* b3 = (const float*)d_in[7];
    float* outp = (float*)d_out;

    char* ws = (char*)d_ws;
    u16* wf1 = (u16*)ws; ws += (size_t)E_EXP * 512 * KP * 2;    // 4.19 MB
    u16* wf2 = (u16*)ws; ws += (size_t)E_EXP * 512 * KP * 2;    // 4.19 MB
    u16* wf3 = (u16*)ws; ws += (size_t)E_EXP * N3PAD * KP * 2;  // 3.15 MB
    u16* xp = (u16*)ws;  ws += (size_t)BATCH * KP * 2;          // 8.39 MB
    u16* h1 = (u16*)ws;  ws += (size_t)BATCH * KP * 2;          // 8.39 MB
    u16* h2 = (u16*)ws;  ws += (size_t)BATCH * KP * 2;          // 8.39 MB
    u16* P = (u16*)ws;                                          // 8192*384*2 = 6.29 MB

    pack_all<<<2048, 256, 0, stream>>>(x, W1, W2, W3, xp, wf1, wf2, wf3);

    gemm_all<<<32 * 8, 1024, 0, stream>>>(xp, wf1, blend, b1, h1, 512, 512, 8, 0);
    gemm_all<<<32 * 8, 1024, 0, stream>>>(h1, wf2, blend, b2, h2, 512, 512, 8, 0);
    gemm_all<<<32 * 6, 1024, 0, stream>>>(h2, wf3, blend, b3, P, N3PAD, D3, 6, 1);
    softmax_rows<<<BATCH, 128, 0, stream>>>(P, outp);
}

// Round 7
// 3750.829 us; speedup vs baseline: 1.0021x; 1.0021x over previous
//
#include <hip/hip_runtime.h>
#include <cstdint>

#define E_EXP 8
#define BATCH 8192
#define D0 480
#define D1 512
#define D2 512
#define D3 363
#define KP 512      // padded per-expert K
#define N3PAD 384

typedef _Float16 f16x8 __attribute__((ext_vector_type(8)));
typedef float f32x4 __attribute__((ext_vector_type(4)));
typedef unsigned short u16;

__device__ __forceinline__ u16 f2h(float f) {
    _Float16 h = (_Float16)f;
    return __builtin_bit_cast(u16, h);
}

// async global->LDS, 16B per lane; LDS dest = wave-uniform base + lane*16
__device__ __forceinline__ void async16(const u16* g, u16* s) {
    __builtin_amdgcn_global_load_lds(
        reinterpret_cast<const __attribute__((address_space(1))) void*>(
            reinterpret_cast<uintptr_t>(g)),
        reinterpret_cast<__attribute__((address_space(3))) void*>(
            reinterpret_cast<uintptr_t>(s)),
        16, 0, 0);
}

// W[e][o][i] fp32 -> wf[e][o][0..511] fp16, zero-padded in o (to OUTP) and i (to 512)
__device__ __forceinline__ void pack_seg(const float* __restrict__ src,
                                         u16* __restrict__ dst,
                                         int OUT_src, int OUTP, int IN_src) {
    int total = E_EXP * OUTP * 128;
    int in4 = IN_src >> 2;
    for (int idx = blockIdx.x * blockDim.x + threadIdx.x; idx < total;
         idx += gridDim.x * blockDim.x) {
        int e = idx / (OUTP * 128);
        int r = idx - e * OUTP * 128;
        int o = r >> 7;
        int k4 = r & 127;
        ushort4 w;
        if (o < OUT_src && k4 < in4) {
            const float4 v = *reinterpret_cast<const float4*>(
                src + ((size_t)e * OUT_src + o) * IN_src + (k4 << 2));
            w.x = f2h(v.x); w.y = f2h(v.y); w.z = f2h(v.z); w.w = f2h(v.w);
        } else {
            w.x = 0; w.y = 0; w.z = 0; w.w = 0;
        }
        *reinterpret_cast<ushort4*>(dst + ((size_t)e * OUTP + o) * KP + (k4 << 2)) = w;
    }
}

// One prep kernel: pack W1/W2/W3 fp32->fp16(padded) AND pad x.
__global__ void pack_all(const float* __restrict__ x,
                         const float* __restrict__ W1, const float* __restrict__ W2,
                         const float* __restrict__ W3, u16* __restrict__ xp,
                         u16* __restrict__ wf1, u16* __restrict__ wf2,
                         u16* __restrict__ wf3) {
    pack_seg(W1, wf1, 512, 512, D0);
    pack_seg(W2, wf2, 512, 512, D1);
    pack_seg(W3, wf3, D3, N3PAD, D2);
    // x (8192x480 fp32) -> xp (8192x512 fp16, zero-padded)
    int total = BATCH * 128;
    for (int idx = blockIdx.x * blockDim.x + threadIdx.x; idx < total;
         idx += gridDim.x * blockDim.x) {
        int b = idx >> 7, k4 = idx & 127;
        ushort4 w;
        if (k4 < 120) {
            const float4 v = *reinterpret_cast<const float4*>(
                x + (size_t)b * D0 + (k4 << 2));
            w.x = f2h(v.x); w.y = f2h(v.y); w.z = f2h(v.z); w.w = f2h(v.w);
        } else {
            w.x = 0; w.y = 0; w.z = 0; w.w = 0;
        }
        *reinterpret_cast<ushort4*>(xp + (size_t)b * KP + (k4 << 2)) = w;
    }
}

// All-expert fused blended GEMM, DOUBLE-BUFFERED (BK=32, 16 passes):
//   acc[m][n] = sum_e bl[e,m] * (A @ W_e^T)[m,n]   (in-register blend on A)
// Tile 256x64 and LDS layout identical to the verified round-0 kernel.
// 16 waves of 64x16 wave-tiles (4m x 4n): 4 waves/SIMD (vs r0's 2) at the
// same tile/LDS/staging -- latency-hiding via wave count.
// ROUND 7 FIX: __launch_bounds__(1024, 1). Round 6's (1024, 4) squeezed the
// VGPR budget to 64 -> full spill (WRITE_SIZE 490MB scratch, FETCH 3GB,
// MfmaUtil 1%). Geometry (96KB LDS -> 1 block/CU) already gives 16 waves/CU;
// the bound only needs to leave the allocator ~128 VGPRs.
// [session ledger: r0/r5 = 43.0-43.4us/gemm (verified). Falsified: 32x32x16
//  (-6%), counted-vmcnt-only (neutral), 128-row-tile blocks (-5%), 4-phase
//  interleave (-130%), launch_bounds reg-squeeze (r6, invalid test).]
__global__ __launch_bounds__(1024, 1) void gemm_all(
    const u16* __restrict__ A, const u16* __restrict__ Bw,
    const float* __restrict__ blend, const float* __restrict__ bias,
    u16* __restrict__ out, int OUTP, int OUTR, int nbn, int mode) {
    __shared__ __align__(16) u16 S[49152];  // 96 KB = 2 x (As 8192 + Bs 16384)
    const int tid = threadIdx.x;
    const int w = tid >> 6, lane = tid & 63;   // 16 waves
    const int wm3 = w & 3, wn3 = w >> 2;       // 4 m-waves x 4 n-waves
    const int q = lane >> 4, l15 = lane & 15;

    const int id = blockIdx.x;
    const int xcd = id & 7;
    const int j = id >> 3;
    const int bm = ((j & 3) << 3) + xcd;  // 0..31 (256-row tiles), pinned to XCD
    const int bn = j >> 2;                // 0..nbn-1

    f32x4 acc[4];  // 4 m-frags x 1 n-frag (wave tile 64x16)
#pragma unroll
    for (int mi = 0; mi < 4; ++mi) acc[mi] = (f32x4){0.f, 0.f, 0.f, 0.f};

    // per-lane blend scalars: blh[e][mi] = blend[e, bm*256 + wm3*64 + mi*16 + l15]
    _Float16 blh[8][4];
#pragma unroll
    for (int e = 0; e < 8; ++e)
#pragma unroll
        for (int mi = 0; mi < 4; ++mi)
            blh[e][mi] = (_Float16)blend[e * BATCH + bm * 256 + wm3 * 64 +
                                         mi * 16 + l15];

    // staging geometry: 1KB chunk = 16 rows x 32k; lane = r*4 + s
    const int l4r = lane >> 2;                 // row in chunk
    const int l4s = lane & 3;                  // phys slot
    const int ks8 = (l4s ^ (l4r & 3)) << 3;    // swizzled k elem offset
    const size_t EST = (size_t)OUTP * KP;      // expert stride in Bw
    // wave w stages: A rows [16w,16w+16) (1 call); B expert w>>1,
    // rows [32*(w&1), +32) (2 calls). 48 x 1KB chunks total per kt.
    const int half = w & 1;
    const u16* gA0 = A + (size_t)(bm * 256 + w * 16 + l4r) * KP + ks8;
    const u16* gB0 = Bw + (size_t)(w >> 1) * EST +
                     (size_t)(bn * 64 + half * 32 + l4r) * KP + ks8;
    const size_t R16 = (size_t)16 * KP;
    const int aBase = w * 512;                          // As dst (elems)
    const int bBase = 8192 + (w >> 1) * 2048 + half * 1024;  // Bs dst

    // fragment read offsets (loop-invariant)
    const int ra = (q ^ (l15 & 3)) << 3;       // swizzled k-slot for reads
    const int arow[4] = {(wm3 * 64 + 0 * 16 + l15) * 32 + ra,
                         (wm3 * 64 + 1 * 16 + l15) * 32 + ra,
                         (wm3 * 64 + 2 * 16 + l15) * 32 + ra,
                         (wm3 * 64 + 3 * 16 + l15) * 32 + ra};
    const int brow = (wn3 * 16 + l15) * 32 + ra;

    auto stage = [&](int kt, int p) {
        const int ko = kt << 5;
        u16* buf = S + p * 24576;
        async16(gA0 + ko, buf + aBase);
        async16(gB0 + ko, buf + bBase);
        async16(gB0 + R16 + ko, buf + bBase + 512);
    };

    stage(0, 0);
    __syncthreads();

#pragma unroll 2
    for (int kt = 0; kt < 16; ++kt) {
        const int p = kt & 1;
        if (kt < 15) stage(kt + 1, p ^ 1);
        const u16* As_ = S + p * 24576;
        const u16* Bs_ = As_ + 8192;
        f16x8 af[4];
#pragma unroll
        for (int mi = 0; mi < 4; ++mi)
            af[mi] = *reinterpret_cast<const f16x8*>(&As_[arow[mi]]);
#pragma unroll
        for (int e = 0; e < 8; ++e) {
            f16x8 bf = *reinterpret_cast<const f16x8*>(&Bs_[e * 2048 + brow]);
#pragma unroll
            for (int mi = 0; mi < 4; ++mi) {
                f16x8 as = af[mi] * blh[e][mi];
                acc[mi] = __builtin_amdgcn_mfma_f32_16x16x32_f16(
                    as, bf, acc[mi], 0, 0, 0);
            }
        }
        __syncthreads();
    }

    // fused epilogue: blended bias from LDS tiles, optional ELU, fp16 store
    float* Blf = reinterpret_cast<float*>(S);           // [256][8]
    float* Bif = reinterpret_cast<float*>(S + 16384);   // [64][8] (32 KB in)
    for (int idx = tid; idx < 2048; idx += 1024) {
        int e = idx >> 8, r = idx & 255;
        Blf[r * 8 + e] = blend[e * BATCH + bm * 256 + r];
    }
    if (tid < 512) {
        int e = tid >> 6, c = tid & 63;
        int cg = bn * 64 + c;
        Bif[c * 8 + e] = (cg < OUTR) ? bias[e * OUTR + cg] : 0.f;
    }
    __syncthreads();

    const int col_l = wn3 * 16 + l15;
    const int gcol = bn * 64 + col_l;
    float bif[8];
#pragma unroll
    for (int e = 0; e < 8; ++e) bif[e] = Bif[col_l * 8 + e];
#pragma unroll
    for (int mi = 0; mi < 4; ++mi) {
#pragma unroll
        for (int r = 0; r < 4; ++r) {
            int rl = wm3 * 64 + mi * 16 + q * 4 + r;
            float bb = 0.f;
#pragma unroll
            for (int e = 0; e < 8; ++e) bb += Blf[rl * 8 + e] * bif[e];
            float v = acc[mi][r] + bb;
            if (mode == 0) v = v > 0.f ? v : expm1f(v);
            out[(size_t)(bm * 256 + rl) * OUTP + gcol] = f2h(v);
        }
    }
}

// softmax over D3=363 of fp16 logits (bias already applied) -> fp32 out.
__global__ __launch_bounds__(128) void softmax_rows(
    const u16* __restrict__ P, float* __restrict__ out) {
    const int b = blockIdx.x;
    const int tid = threadIdx.x, lane = tid & 63, w = tid >> 6;
    float v[3];
    int n = 0;
    float mx = -3.4e38f;
    for (int i = tid; i < D3; i += 128) {
        float s = (float)*reinterpret_cast<const _Float16*>(
            P + (size_t)b * N3PAD + i);
        v[n] = s; mx = fmaxf(mx, s); ++n;
    }
#pragma unroll
    for (int off = 32; off >= 1; off >>= 1) mx = fmaxf(mx, __shfl_xor(mx, off, 64));
    __shared__ float sm[4];
    if (lane == 0) sm[w] = mx;
    __syncthreads();
    mx = fmaxf(sm[0], sm[1]);
    float s = 0.f;
    for (int jj = 0; jj < n; ++jj) { v[jj] = expf(v[jj] - mx); s += v[jj]; }
#pragma unroll
    for (int off = 32; off >= 1; off >>= 1) s += __shfl_xor(s, off, 64);
    if (lane == 0) sm[2 + w] = s;
    __syncthreads();
    float inv = 1.f / (sm[2] + sm[3]);
    n = 0;
    for (int i = tid; i < D3; i += 128) { out[(size_t)b * D3 + i] = v[n] * inv; ++n; }
}

extern "C" void kernel_launch(void* const* d_in, const int* in_sizes, int n_in,
                              void* d_out, int out_size, void* d_ws, size_t ws_size,
                              hipStream_t stream) {
    const float* x = (const float*)d_in[0];
    const float* blend = (const float*)d_in[1];
    const float* W1 = (const float*)d_in[2];
    const float* b1 = (const float*)d_in[3];
    const float* W2 = (const float*)d_in[4];
    const float* b2 = (const float*)d_in[5];
    const float* W3 = (const float*)d_in[6];
    const float* b3 = (const float*)d_in[7];
    float* outp = (float*)d_out;

    char* ws = (char*)d_ws;
    u16* wf1 = (u16*)ws; ws += (size_t)E_EXP * 512 * KP * 2;    // 4.19 MB
    u16* wf2 = (u16*)ws; ws += (size_t)E_EXP * 512 * KP * 2;    // 4.19 MB
    u16* wf3 = (u16*)ws; ws += (size_t)E_EXP * N3PAD * KP * 2;  // 3.15 MB
    u16* xp = (u16*)ws;  ws += (size_t)BATCH * KP * 2;          // 8.39 MB
    u16* h1 = (u16*)ws;  ws += (size_t)BATCH * KP * 2;          // 8.39 MB
    u16* h2 = (u16*)ws;  ws += (size_t)BATCH * KP * 2;          // 8.39 MB
    u16* P = (u16*)ws;                                          // 8192*384*2 = 6.29 MB

    pack_all<<<2048, 256, 0, stream>>>(x, W1, W2, W3, xp, wf1, wf2, wf3);

    gemm_all<<<32 * 8, 1024, 0, stream>>>(xp, wf1, blend, b1, h1, 512, 512, 8, 0);
    gemm_all<<<32 * 8, 1024, 0, stream>>>(h1, wf2, blend, b2, h2, 512, 512, 8, 0);
    gemm_all<<<32 * 6, 1024, 0, stream>>>(h2, wf3, blend, b3, P, N3PAD, D3, 6, 1);
    softmax_rows<<<BATCH, 128, 0, stream>>>(P, outp);
}

// Round 8
// 3477.021 us; speedup vs baseline: 1.0810x; 1.0787x over previous
//
#include <hip/hip_runtime.h>
#include <cstdint>

#define E_EXP 8
#define BATCH 8192
#define D0 480
#define D1 512
#define D2 512
#define D3 363
#define KP 512      // padded per-expert K
#define N3PAD 384

typedef _Float16 f16x8 __attribute__((ext_vector_type(8)));
typedef float f32x4 __attribute__((ext_vector_type(4)));
typedef unsigned short u16;

__device__ __forceinline__ u16 f2h(float f) {
    _Float16 h = (_Float16)f;
    return __builtin_bit_cast(u16, h);
}

// async global->LDS, 16B per lane; LDS dest = wave-uniform base + lane*16
__device__ __forceinline__ void async16(const u16* g, u16* s) {
    __builtin_amdgcn_global_load_lds(
        reinterpret_cast<const __attribute__((address_space(1))) void*>(
            reinterpret_cast<uintptr_t>(g)),
        reinterpret_cast<__attribute__((address_space(3))) void*>(
            reinterpret_cast<uintptr_t>(s)),
        16, 0, 0);
}

// W[e][o][i] fp32 -> wf[e][o][0..511] fp16, zero-padded in o (to OUTP) and i (to 512)
__device__ __forceinline__ void pack_seg(const float* __restrict__ src,
                                         u16* __restrict__ dst,
                                         int OUT_src, int OUTP, int IN_src) {
    int total = E_EXP * OUTP * 128;
    int in4 = IN_src >> 2;
    for (int idx = blockIdx.x * blockDim.x + threadIdx.x; idx < total;
         idx += gridDim.x * blockDim.x) {
        int e = idx / (OUTP * 128);
        int r = idx - e * OUTP * 128;
        int o = r >> 7;
        int k4 = r & 127;
        ushort4 w;
        if (o < OUT_src && k4 < in4) {
            const float4 v = *reinterpret_cast<const float4*>(
                src + ((size_t)e * OUT_src + o) * IN_src + (k4 << 2));
            w.x = f2h(v.x); w.y = f2h(v.y); w.z = f2h(v.z); w.w = f2h(v.w);
        } else {
            w.x = 0; w.y = 0; w.z = 0; w.w = 0;
        }
        *reinterpret_cast<ushort4*>(dst + ((size_t)e * OUTP + o) * KP + (k4 << 2)) = w;
    }
}

// One prep kernel: pack W1/W2/W3 fp32->fp16(padded) AND pad x.
__global__ void pack_all(const float* __restrict__ x,
                         const float* __restrict__ W1, const float* __restrict__ W2,
                         const float* __restrict__ W3, u16* __restrict__ xp,
                         u16* __restrict__ wf1, u16* __restrict__ wf2,
                         u16* __restrict__ wf3) {
    pack_seg(W1, wf1, 512, 512, D0);
    pack_seg(W2, wf2, 512, 512, D1);
    pack_seg(W3, wf3, D3, N3PAD, D2);
    // x (8192x480 fp32) -> xp (8192x512 fp16, zero-padded)
    int total = BATCH * 128;
    for (int idx = blockIdx.x * blockDim.x + threadIdx.x; idx < total;
         idx += gridDim.x * blockDim.x) {
        int b = idx >> 7, k4 = idx & 127;
        ushort4 w;
        if (k4 < 120) {
            const float4 v = *reinterpret_cast<const float4*>(
                x + (size_t)b * D0 + (k4 << 2));
            w.x = f2h(v.x); w.y = f2h(v.y); w.z = f2h(v.z); w.w = f2h(v.w);
        } else {
            w.x = 0; w.y = 0; w.z = 0; w.w = 0;
        }
        *reinterpret_cast<ushort4*>(xp + (size_t)b * KP + (k4 << 2)) = w;
    }
}

// All-expert fused blended GEMM, DOUBLE-BUFFERED (BK=32, 16 passes):
//   acc[m][n] = sum_e bl[e,m] * (A @ W_e^T)[m,n]   (in-register blend on A)
// ROUND 8: 4 waves/SIMD via TWO 512-thread blocks per CU (not one 1024-thread
// block -- hipcc pins 1024-thr blocks to 64 VGPR -> r6/r7 full spill).
// Block tile 128x64, 8 waves of 64x16 wave-tiles (2m x 4n). Per-buffer LDS:
// As 128x32 (8KB) + Bs 8e x 64n x 32k (32KB) = 40KB; x2 = 80KB -> exactly
// 2 blocks/CU = 16 waves/CU. VGPR law (m69): pool ~2048/CU -> 4 waves/SIMD
// needs <=128 VGPR; this kernel's state (~100) fits; launch_bounds(512,4)
// sets the cap. Per-wave inner loop = r6 design: 12 b128 reads -> 32 MFMA,
// 4 independent chains. Per-CU MFMA work unchanged; LDS reads +20%.
// [ledger: r0/r5 = 43.0-43.4us/gemm verified best. Falsified: 32x32x16 (-6%),
//  counted-vmcnt-only (0), 4-wave-block pairs (-5%), 4-phase (-130%),
//  1024-thr blocks (spill, invalid). Decisive counter: OccupancyPercent.]
__global__ __launch_bounds__(512, 4) void gemm_all(
    const u16* __restrict__ A, const u16* __restrict__ Bw,
    const float* __restrict__ blend, const float* __restrict__ bias,
    u16* __restrict__ out, int OUTP, int OUTR, int nbn, int mode) {
    __shared__ __align__(16) u16 S[40960];  // 80 KB = 2 x (As 4096 + Bs 16384)
    const int tid = threadIdx.x;
    const int w = tid >> 6, lane = tid & 63;   // 8 waves
    const int wm = w & 1, wn = w >> 1;         // 2 m-waves x 4 n-waves
    const int q = lane >> 4, l15 = lane & 15;

    const int id = blockIdx.x;
    const int xcd = id & 7;
    const int j = id >> 3;
    const int bm = ((j & 7) << 3) + xcd;  // 0..63 (128-row tiles), pinned to XCD
    const int bn = j >> 3;                // 0..nbn-1

    f32x4 acc[4];  // 4 m-frags x 1 n-frag (wave tile 64x16)
#pragma unroll
    for (int mi = 0; mi < 4; ++mi) acc[mi] = (f32x4){0.f, 0.f, 0.f, 0.f};

    // per-lane blend scalars: blh[e][mi] = blend[e, bm*128 + wm*64 + mi*16 + l15]
    _Float16 blh[8][4];
#pragma unroll
    for (int e = 0; e < 8; ++e)
#pragma unroll
        for (int mi = 0; mi < 4; ++mi)
            blh[e][mi] = (_Float16)blend[e * BATCH + bm * 128 + wm * 64 +
                                         mi * 16 + l15];

    // staging geometry: 1KB chunk = 16 rows x 32k; lane = r*4 + s
    const int l4r = lane >> 2;                 // row in chunk
    const int l4s = lane & 3;                  // phys slot
    const int ks8 = (l4s ^ (l4r & 3)) << 3;    // swizzled k elem offset
    const size_t EST = (size_t)OUTP * KP;      // expert stride in Bw
    // wave w stages: A rows [16w,16w+16) (1 chunk) + expert w's 64 rows
    // (4 chunks) = 5 async16/wave, 40 chunks = 40KB/buffer total.
    const u16* gA0 = A + (size_t)(bm * 128 + w * 16 + l4r) * KP + ks8;
    const u16* gB0 = Bw + (size_t)w * EST + (size_t)(bn * 64 + l4r) * KP + ks8;
    const size_t R16 = (size_t)16 * KP;
    const int aBase = w * 512;                 // As dst (elems, within buffer)
    const int bBase = 4096 + w * 2048;         // Bs dst (wave w stages expert w)

    // fragment read offsets (loop-invariant)
    const int ra = (q ^ (l15 & 3)) << 3;       // swizzled k-slot for reads
    const int arow[4] = {(wm * 64 + 0 * 16 + l15) * 32 + ra,
                         (wm * 64 + 1 * 16 + l15) * 32 + ra,
                         (wm * 64 + 2 * 16 + l15) * 32 + ra,
                         (wm * 64 + 3 * 16 + l15) * 32 + ra};
    const int brow = (wn * 16 + l15) * 32 + ra;

    auto stage = [&](int kt, int p) {
        const int ko = kt << 5;
        u16* buf = S + p * 20480;
        async16(gA0 + ko, buf + aBase);
        async16(gB0 + ko, buf + bBase);
        async16(gB0 + R16 + ko, buf + bBase + 512);
        async16(gB0 + 2 * R16 + ko, buf + bBase + 1024);
        async16(gB0 + 3 * R16 + ko, buf + bBase + 1536);
    };

    stage(0, 0);
    __syncthreads();

#pragma unroll 2
    for (int kt = 0; kt < 16; ++kt) {
        const int p = kt & 1;
        if (kt < 15) stage(kt + 1, p ^ 1);
        const u16* As_ = S + p * 20480;
        const u16* Bs_ = As_ + 4096;
        f16x8 af[4];
#pragma unroll
        for (int mi = 0; mi < 4; ++mi)
            af[mi] = *reinterpret_cast<const f16x8*>(&As_[arow[mi]]);
#pragma unroll
        for (int e = 0; e < 8; ++e) {
            f16x8 bf = *reinterpret_cast<const f16x8*>(&Bs_[e * 2048 + brow]);
#pragma unroll
            for (int mi = 0; mi < 4; ++mi) {
                f16x8 as = af[mi] * blh[e][mi];
                acc[mi] = __builtin_amdgcn_mfma_f32_16x16x32_f16(
                    as, bf, acc[mi], 0, 0, 0);
            }
        }
        __syncthreads();
    }

    // fused epilogue: blended bias from LDS tiles, optional ELU, fp16 store
    float* Blf = reinterpret_cast<float*>(S);          // [128][8] (4KB)
    float* Bif = reinterpret_cast<float*>(S + 4096);   // [64][8]  (byte 8192)
    for (int idx = tid; idx < 1024; idx += 512) {
        int e = idx >> 7, r = idx & 127;
        Blf[r * 8 + e] = blend[e * BATCH + bm * 128 + r];
    }
    {
        int e = tid >> 6, c = tid & 63;
        int cg = bn * 64 + c;
        Bif[c * 8 + e] = (cg < OUTR) ? bias[e * OUTR + cg] : 0.f;
    }
    __syncthreads();

    const int col_l = wn * 16 + l15;
    const int gcol = bn * 64 + col_l;
    float bif[8];
#pragma unroll
    for (int e = 0; e < 8; ++e) bif[e] = Bif[col_l * 8 + e];
#pragma unroll
    for (int mi = 0; mi < 4; ++mi) {
#pragma unroll
        for (int r = 0; r < 4; ++r) {
            int rl = wm * 64 + mi * 16 + q * 4 + r;
            float bb = 0.f;
#pragma unroll
            for (int e = 0; e < 8; ++e) bb += Blf[rl * 8 + e] * bif[e];
            float v = acc[mi][r] + bb;
            if (mode == 0) v = v > 0.f ? v : expm1f(v);
            out[(size_t)(bm * 128 + rl) * OUTP + gcol] = f2h(v);
        }
    }
}

// softmax over D3=363 of fp16 logits (bias already applied) -> fp32 out.
__global__ __launch_bounds__(128) void softmax_rows(
    const u16* __restrict__ P, float* __restrict__ out) {
    const int b = blockIdx.x;
    const int tid = threadIdx.x, lane = tid & 63, w = tid >> 6;
    float v[3];
    int n = 0;
    float mx = -3.4e38f;
    for (int i = tid; i < D3; i += 128) {
        float s = (float)*reinterpret_cast<const _Float16*>(
            P + (size_t)b * N3PAD + i);
        v[n] = s; mx = fmaxf(mx, s); ++n;
    }
#pragma unroll
    for (int off = 32; off >= 1; off >>= 1) mx = fmaxf(mx, __shfl_xor(mx, off, 64));
    __shared__ float sm[4];
    if (lane == 0) sm[w] = mx;
    __syncthreads();
    mx = fmaxf(sm[0], sm[1]);
    float s = 0.f;
    for (int jj = 0; jj < n; ++jj) { v[jj] = expf(v[jj] - mx); s += v[jj]; }
#pragma unroll
    for (int off = 32; off >= 1; off >>= 1) s += __shfl_xor(s, off, 64);
    if (lane == 0) sm[2 + w] = s;
    __syncthreads();
    float inv = 1.f / (sm[2] + sm[3]);
    n = 0;
    for (int i = tid; i < D3; i += 128) { out[(size_t)b * D3 + i] = v[n] * inv; ++n; }
}

extern "C" void kernel_launch(void* const* d_in, const int* in_sizes, int n_in,
                              void* d_out, int out_size, void* d_ws, size_t ws_size,
                              hipStream_t stream) {
    const float* x = (const float*)d_in[0];
    const float* blend = (const float*)d_in[1];
    const float* W1 = (const float*)d_in[2];
    const float* b1 = (const float*)d_in[3];
    const float* W2 = (const float*)d_in[4];
    const float* b2 = (const float*)d_in[5];
    const float* W3 = (const float*)d_in[6];
    const float* b3 = (const float*)d_in[7];
    float* outp = (float*)d_out;

    char* ws = (char*)d_ws;
    u16* wf1 = (u16*)ws; ws += (size_t)E_EXP * 512 * KP * 2;    // 4.19 MB
    u16* wf2 = (u16*)ws; ws += (size_t)E_EXP * 512 * KP * 2;    // 4.19 MB
    u16* wf3 = (u16*)ws; ws += (size_t)E_EXP * N3PAD * KP * 2;  // 3.15 MB
    u16* xp = (u16*)ws;  ws += (size_t)BATCH * KP * 2;          // 8.39 MB
    u16* h1 = (u16*)ws;  ws += (size_t)BATCH * KP * 2;          // 8.39 MB
    u16* h2 = (u16*)ws;  ws += (size_t)BATCH * KP * 2;          // 8.39 MB
    u16* P = (u16*)ws;                                          // 8192*384*2 = 6.29 MB

    pack_all<<<2048, 256, 0, stream>>>(x, W1, W2, W3, xp, wf1, wf2, wf3);

    gemm_all<<<64 * 8, 512, 0, stream>>>(xp, wf1, blend, b1, h1, 512, 512, 8, 0);
    gemm_all<<<64 * 8, 512, 0, stream>>>(h1, wf2, blend, b2, h2, 512, 512, 8, 0);
    gemm_all<<<64 * 6, 512, 0, stream>>>(h2, wf3, blend, b3, P, N3PAD, D3, 6, 1);
    softmax_rows<<<BATCH, 128, 0, stream>>>(P, outp);
}